// Round 1
// baseline (290.693 us; speedup 1.0000x reference)
//
#include <hip/hip_runtime.h>

// segment_sum: out[g, f] = sum over rows r with batch[r]==g of x[r, f]
// x: (200000, 256) f32 row-major; batch: (200000,) int (sorted); out: (512, 256) f32
//
// Strategy: batch is sorted -> each wave walks a contiguous row range with a
// per-lane float4 register accumulator, flushing via atomicAdd only on
// segment-id change. One wave reads one full row per iteration (64 lanes x
// 16B = 1024B, fully coalesced). ~1.6M atomics total vs 51M naive.

#define FEAT 256
#define WAVES_PER_BLOCK 4
#define NUM_BLOCKS 1024

__global__ __launch_bounds__(256) void GraphAddPooling_39539468927441_kernel(
    const float* __restrict__ x, const int* __restrict__ batch,
    float* __restrict__ out, int n_rows, int rows_per_block)
{
    const int lane = threadIdx.x & 63;   // float4 group within the row
    const int wave = threadIdx.x >> 6;   // 0..3

    const int r0 = blockIdx.x * rows_per_block;
    int r1 = r0 + rows_per_block;
    if (r1 > n_rows) r1 = n_rows;

    const float4* __restrict__ x4 = (const float4*)x;  // 64 float4 per row

    float4 acc = make_float4(0.f, 0.f, 0.f, 0.f);
    int cur = -1;  // current segment id held in acc

    for (int r = r0 + wave; r < r1; r += WAVES_PER_BLOCK) {
        const int g = batch[r];                       // wave-uniform broadcast
        const float4 v = x4[(size_t)r * (FEAT / 4) + lane];
        if (g != cur) {                               // wave-uniform branch
            if (cur >= 0) {
                float* o = out + (size_t)cur * FEAT + lane * 4;
                atomicAdd(o + 0, acc.x);
                atomicAdd(o + 1, acc.y);
                atomicAdd(o + 2, acc.z);
                atomicAdd(o + 3, acc.w);
            }
            cur = g;
            acc = make_float4(0.f, 0.f, 0.f, 0.f);
        }
        acc.x += v.x; acc.y += v.y; acc.z += v.z; acc.w += v.w;
    }
    if (cur >= 0) {
        float* o = out + (size_t)cur * FEAT + lane * 4;
        atomicAdd(o + 0, acc.x);
        atomicAdd(o + 1, acc.y);
        atomicAdd(o + 2, acc.z);
        atomicAdd(o + 3, acc.w);
    }
}

extern "C" void kernel_launch(void* const* d_in, const int* in_sizes, int n_in,
                              void* d_out, int out_size, void* d_ws, size_t ws_size,
                              hipStream_t stream) {
    const float* x     = (const float*)d_in[0];
    const int*   batch = (const int*)d_in[1];
    float*       out   = (float*)d_out;

    const int n_rows = in_sizes[1];  // 200000

    // d_out is poisoned with 0xAA before every launch -> zero it (capture-safe).
    hipMemsetAsync(d_out, 0, (size_t)out_size * sizeof(float), stream);

    const int rows_per_block = (n_rows + NUM_BLOCKS - 1) / NUM_BLOCKS;
    GraphAddPooling_39539468927441_kernel<<<NUM_BLOCKS, 256, 0, stream>>>(
        x, batch, out, n_rows, rows_per_block);
}

// Round 2
// 282.011 us; speedup vs baseline: 1.0308x; 1.0308x over previous
//
#include <hip/hip_runtime.h>

// segment_sum: out[g, f] = sum over rows r with batch[r]==g of x[r, f]
// x: (200000, 256) f32 row-major; batch: (200000,) int32 (SORTED); out: (512, 256) f32
//
// Two-kernel plan:
//  1. seg_bounds: start[g] = first row r with batch[r] >= g, start[512] = n.
//     Each boundary written by exactly one thread (the first occurrence).
//  2. pool: one block per segment g. Rows [start[g], start[g+1]) are streamed
//     branch-free: 4 waves interleave rows, 16B/lane float4 loads, unroll x4
//     (4 loads in flight per wave). Cross-wave partials reduced through 4KB
//     LDS; out[g] written exactly once (empty segments write zeros) -> no
//     memset, no atomics.

#define FEAT 256
#define F4   (FEAT / 4)   // 64 float4 per row == one wave-load per row
#define NSEG 512

__global__ void seg_bounds_kernel(const int* __restrict__ batch,
                                  int* __restrict__ start, int n) {
    int r = blockIdx.x * blockDim.x + threadIdx.x;
    if (r >= n) return;
    int cur = batch[r];
    if (r == 0) {
        for (int g = 0; g <= cur; ++g) start[g] = 0;
    } else {
        int prev = batch[r - 1];
        for (int g = prev + 1; g <= cur; ++g) start[g] = r;
    }
    if (r == n - 1) {
        for (int g = cur + 1; g <= NSEG; ++g) start[g] = n;
    }
}

__global__ __launch_bounds__(256) void GraphAddPooling_39539468927441_kernel(
    const float* __restrict__ x, const int* __restrict__ start,
    float* __restrict__ out)
{
    const int g    = blockIdx.x;          // segment id == output row
    const int lane = threadIdx.x & 63;    // float4 column group within row
    const int wave = threadIdx.x >> 6;    // 0..3, interleaved over rows

    const int r0 = start[g];
    const int r1 = start[g + 1];

    const float4* __restrict__ x4 = (const float4*)x;

    float4 a0 = make_float4(0.f, 0.f, 0.f, 0.f);
    float4 a1 = a0, a2 = a0, a3 = a0;

    int r = r0 + wave;
    // Unroll x4: rows r, r+4, r+8, r+12 (wave stride 4, block covers all rows).
    // All 4 loads issue before any accumulate -> 4 memory ops in flight/wave.
    for (; r + 12 < r1; r += 16) {
        float4 v0 = x4[(size_t)r        * F4 + lane];
        float4 v1 = x4[(size_t)(r + 4)  * F4 + lane];
        float4 v2 = x4[(size_t)(r + 8)  * F4 + lane];
        float4 v3 = x4[(size_t)(r + 12) * F4 + lane];
        a0.x += v0.x; a0.y += v0.y; a0.z += v0.z; a0.w += v0.w;
        a1.x += v1.x; a1.y += v1.y; a1.z += v1.z; a1.w += v1.w;
        a2.x += v2.x; a2.y += v2.y; a2.z += v2.z; a2.w += v2.w;
        a3.x += v3.x; a3.y += v3.y; a3.z += v3.z; a3.w += v3.w;
    }
    for (; r < r1; r += 4) {
        float4 v = x4[(size_t)r * F4 + lane];
        a0.x += v.x; a0.y += v.y; a0.z += v.z; a0.w += v.w;
    }
    a0.x += a1.x + a2.x + a3.x;
    a0.y += a1.y + a2.y + a3.y;
    a0.z += a1.z + a2.z + a3.z;
    a0.w += a1.w + a2.w + a3.w;

    // Cross-wave reduction: 4 partials per (lane) column.
    __shared__ float4 red[4][F4];   // 4 KB
    red[wave][lane] = a0;
    __syncthreads();
    if (wave == 0) {
        float4 s = red[0][lane];
        float4 b = red[1][lane], c = red[2][lane], d = red[3][lane];
        s.x += b.x + c.x + d.x;
        s.y += b.y + c.y + d.y;
        s.z += b.z + c.z + d.z;
        s.w += b.w + c.w + d.w;
        ((float4*)out)[(size_t)g * F4 + lane] = s;
    }
}

extern "C" void kernel_launch(void* const* d_in, const int* in_sizes, int n_in,
                              void* d_out, int out_size, void* d_ws, size_t ws_size,
                              hipStream_t stream) {
    const float* x     = (const float*)d_in[0];
    const int*   batch = (const int*)d_in[1];
    float*       out   = (float*)d_out;
    int*         start = (int*)d_ws;     // 513 ints, rewritten every call

    const int n_rows = in_sizes[1];      // 200000

    seg_bounds_kernel<<<(n_rows + 255) / 256, 256, 0, stream>>>(batch, start, n_rows);
    GraphAddPooling_39539468927441_kernel<<<NSEG, 256, 0, stream>>>(x, start, out);
}